// Round 1
// baseline (388.119 us; speedup 1.0000x reference)
//
#include <hip/hip_runtime.h>
#include <math.h>

#define B_ 16
#define C_ 3
#define H_ 512
#define W_ 512
#define HW_ (H_*W_)              // 262144
#define NFULL (B_*C_*HW_)        // 12582912
#define NHALF (B_*HW_)           // 4194304
#define OUTW 506                 // 512-7+1
#define ROWS 32                  // output rows per SSIM strip
#define CW 528                   // padded LDS row width (512 + slack for 4t+11 reads)

#define INV49 (1.0f/49.0f)
#define COVN  (49.0f/48.0f)
#define C1f   (1e-4f)
#define C2f   (9e-4f)

__device__ __forceinline__ float wred(float v){
  v += __shfl_down(v,32); v += __shfl_down(v,16); v += __shfl_down(v,8);
  v += __shfl_down(v,4);  v += __shfl_down(v,2);  v += __shfl_down(v,1);
  return v;
}

// ---------------- kernel 1: fused elementwise reductions ----------------
__global__ __launch_bounds__(256) void k_elem(
    const float4* __restrict__ img, const float4* __restrict__ tgt,
    const float4* __restrict__ c0,  const float4* __restrict__ c1,
    const float4* __restrict__ c2,  const float4* __restrict__ r0,
    const float4* __restrict__ r1,  double* __restrict__ acc){
  const int tid = blockIdx.x*256 + threadIdx.x;
  const int nth = gridDim.x*256;
  float s0=0.f,s1=0.f,s2=0.f,s3=0.f,s4=0.f;
  const int N4 = NFULL/4, M4 = NHALF/4;
  const int CHW4 = C_*HW_/4;     // 196608
  const int HW4m = HW_/4 - 1;    // 65535
  for(int m=tid; m<N4; m+=nth){
    int b = m / CHW4;
    int cidx = b*(HW_/4) + (m & HW4m);
    float4 a=c0[m], r=r0[m], im=img[m], tg=tgt[m], o=c1[cidx], q=r1[cidx];
    s0 += fabsf(a.x-r.x)+fabsf(a.y-r.y)+fabsf(a.z-r.z)+fabsf(a.w-r.w);
    s1 += fabsf(im.x-a.x*o.x)+fabsf(im.y-a.y*o.y)+fabsf(im.z-a.z*o.z)+fabsf(im.w-a.w*o.w);
    s2 += fabsf(tg.x-r.x*q.x)+fabsf(tg.y-r.y*q.y)+fabsf(tg.z-r.z*q.z)+fabsf(tg.w-r.w*q.w);
    float dx=im.x-tg.x, dy=im.y-tg.y, dz=im.z-tg.z, dw=im.w-tg.w;
    s3 += dx*dx+dy*dy+dz*dz+dw*dw;
  }
  for(int m=tid; m<M4; m+=nth){
    float4 a=c2[m], r=r1[m];
    float dx=a.x-r.x, dy=a.y-r.y, dz=a.z-r.z, dw=a.w-r.w;
    s4 += dx*dx+dy*dy+dz*dz+dw*dw;
  }
  __shared__ float sred[4][5];
  const int wid=threadIdx.x>>6, lane=threadIdx.x&63;
  float v0=wred(s0), v1=wred(s1), v2=wred(s2), v3=wred(s3), v4=wred(s4);
  if(lane==0){ sred[wid][0]=v0; sred[wid][1]=v1; sred[wid][2]=v2; sred[wid][3]=v3; sred[wid][4]=v4; }
  __syncthreads();
  if(threadIdx.x==0){
    #pragma unroll
    for(int q5=0;q5<5;q5++){
      float t=sred[0][q5]+sred[1][q5]+sred[2][q5]+sred[3][q5];
      atomicAdd(&acc[q5],(double)t);
    }
  }
}

// ---------------- kernel 2: per-(b,c) 256-bin histogram of round(target*255) ----------------
__global__ __launch_bounds__(256) void k_hist(const float4* __restrict__ tgt,
                                              unsigned int* __restrict__ bins){
  __shared__ unsigned int sh[256];
  const int imgi = blockIdx.y;                 // 0..47
  sh[threadIdx.x]=0u;
  __syncthreads();
  const float4* t4 = tgt + (size_t)imgi*(HW_/4);
  const int per = (HW_/4)/8;                   // 8192 float4 per block
  const int base = blockIdx.x*per;
  for(int i=threadIdx.x; i<per; i+=256){
    float4 v = t4[base+i];
    int i0 = __float2int_rn(v.x*255.0f); i0 = min(max(i0,0),255);
    int i1 = __float2int_rn(v.y*255.0f); i1 = min(max(i1,0),255);
    int i2 = __float2int_rn(v.z*255.0f); i2 = min(max(i2,0),255);
    int i3 = __float2int_rn(v.w*255.0f); i3 = min(max(i3,0),255);
    atomicAdd(&sh[i0],1u); atomicAdd(&sh[i1],1u);
    atomicAdd(&sh[i2],1u); atomicAdd(&sh[i3],1u);
  }
  __syncthreads();
  atomicAdd(&bins[imgi*256+threadIdx.x], sh[threadIdx.x]);
}

// ---------------- kernel 3: SSIM (two image pairs), separable 7x7 sliding window ----------------
__device__ __forceinline__ void upd5(float4&cx,float4&cy,float4&cxx,float4&cyy,float4&cxy,
                                     const float4 xv,const float4 yv,const float s){
  cx.x += s*xv.x; cx.y += s*xv.y; cx.z += s*xv.z; cx.w += s*xv.w;
  cy.x += s*yv.x; cy.y += s*yv.y; cy.z += s*yv.z; cy.w += s*yv.w;
  cxx.x += s*xv.x*xv.x; cxx.y += s*xv.y*xv.y; cxx.z += s*xv.z*xv.z; cxx.w += s*xv.w*xv.w;
  cyy.x += s*yv.x*yv.x; cyy.y += s*yv.y*yv.y; cyy.z += s*yv.z*yv.z; cyy.w += s*yv.w*yv.w;
  cxy.x += s*xv.x*yv.x; cxy.y += s*xv.y*yv.y; cxy.z += s*xv.z*yv.z; cxy.w += s*xv.w*yv.w;
}

__global__ __launch_bounds__(128) void k_ssim(
    const float* __restrict__ xA, const float* __restrict__ yA,
    const float* __restrict__ xB, const float* __restrict__ yB,
    double* __restrict__ acc){
  __shared__ __align__(16) float lds[2][5][CW];
  __shared__ float sw[2];
  const int imgid = blockIdx.y;                 // 0..95
  const int pair  = imgid / (B_*C_);            // 0 or 1
  const int bc    = imgid % (B_*C_);
  const float* xim = (pair ? xB : xA) + (size_t)bc*HW_;
  const float* yim = (pair ? yB : yA) + (size_t)bc*HW_;
  const int i0   = blockIdx.x*ROWS;
  const int iEnd = min(i0+ROWS, OUTW);
  const int t = threadIdx.x;
  const int c = 4*t;                            // 4 columns per lane, c in 0..508

  float4 cx={0.f,0.f,0.f,0.f}, cy=cx, cxx=cx, cyy=cx, cxy=cx;
  // init vertical window over rows i0..i0+6
  #pragma unroll 1
  for(int r=i0; r<i0+7; ++r){
    float4 xv = *(const float4*)(xim + (size_t)r*W_ + c);
    float4 yv = *(const float4*)(yim + (size_t)r*W_ + c);
    upd5(cx,cy,cxx,cyy,cxy, xv,yv, 1.0f);
  }

  float accS = 0.f;
  for(int i=i0; i<iEnd; ++i){
    const int buf = i&1;
    *(float4*)&lds[buf][0][c] = cx;
    *(float4*)&lds[buf][1][c] = cy;
    *(float4*)&lds[buf][2][c] = cxx;
    *(float4*)&lds[buf][3][c] = cyy;
    *(float4*)&lds[buf][4][c] = cxy;
    float4 xn,yn,xo,yo;
    const bool upd = (i+1 < iEnd);
    if(upd){
      xn = *(const float4*)(xim + (size_t)(i+7)*W_ + c);
      yn = *(const float4*)(yim + (size_t)(i+7)*W_ + c);
      xo = *(const float4*)(xim + (size_t)i*W_ + c);
      yo = *(const float4*)(yim + (size_t)i*W_ + c);
    }
    __syncthreads();
    if(c < OUTW){
      float hx[4],hy[4],hxx[4],hyy[4],hxy[4];
      auto hsum=[&](const float* p, float* h){
        float4 A=*(const float4*)p; float4 Bv=*(const float4*)(p+4);
        float2 D=*(const float2*)(p+8);
        float s=A.x+A.y+A.z+A.w+Bv.x+Bv.y+Bv.z;
        h[0]=s; s+=Bv.w-A.x; h[1]=s; s+=D.x-A.y; h[2]=s; s+=D.y-A.z; h[3]=s;
      };
      hsum(&lds[buf][0][c], hx);
      hsum(&lds[buf][1][c], hy);
      hsum(&lds[buf][2][c], hxx);
      hsum(&lds[buf][3][c], hyy);
      hsum(&lds[buf][4][c], hxy);
      #pragma unroll
      for(int k=0;k<4;k++){
        if(c+k < OUTW){
          float sx=hx[k], sy=hy[k], sxx=hxx[k], syy=hyy[k], sxy=hxy[k];
          float ux=sx*INV49, uy=sy*INV49;
          float uxuy=ux*uy;
          float vx=COVN*(sxx*INV49-ux*ux);
          float vy=COVN*(syy*INV49-uy*uy);
          float vxy=COVN*(sxy*INV49-uxuy);
          float num=(2.f*uxuy+C1f)*(2.f*vxy+C2f);
          float den=(ux*ux+uy*uy+C1f)*(vx+vy+C2f);
          accS += num/den;
        }
      }
    }
    if(upd){
      upd5(cx,cy,cxx,cyy,cxy, xn,yn,  1.0f);
      upd5(cx,cy,cxx,cyy,cxy, xo,yo, -1.0f);
    }
  }
  // block reduce
  float r = wred(accS);
  if((threadIdx.x&63)==0) sw[threadIdx.x>>6]=r;
  __syncthreads();
  if(threadIdx.x==0) atomicAdd(&acc[6+pair], (double)(sw[0]+sw[1]));
}

// ---------------- kernel 4: color loss + GAN loss + final combine ----------------
__global__ __launch_bounds__(256) void k_final(
    const float* __restrict__ chist, const float* __restrict__ score,
    const double* __restrict__ acc, const unsigned int* __restrict__ bins,
    float* __restrict__ out){
  const int tid = threadIdx.x;
  float cpart = 0.f;
  for(int i=tid; i<B_*C_*256; i+=256){
    float h = (float)bins[i] * (1.0f/(float)HW_);
    cpart += fabsf(chist[i]-h);
  }
  float gpart = 0.f;
  if(tid < B_){
    float x = -score[tid];
    gpart = (x > 0.f) ? (x + log1pf(expf(-x))) : log1pf(expf(x));
  }
  __shared__ float sc[4], sg[4];
  float rc=wred(cpart), rg=wred(gpart);
  const int wid=tid>>6, lane=tid&63;
  if(lane==0){ sc[wid]=rc; sg[wid]=rg; }
  __syncthreads();
  if(tid==0){
    float colorsum = sc[0]+sc[1]+sc[2]+sc[3];
    float gansum   = sg[0]+sg[1]+sg[2]+sg[3];
    double nfull = (double)NFULL;
    double m0 = acc[0]/nfull, m1 = acc[1]/nfull, m2 = acc[2]/nfull, mse = acc[3]/nfull;
    double light = acc[4]/(double)NHALF;
    double nss = (double)(B_*C_) * (double)OUTW * (double)OUTW;  // 12289728
    double ssimA = acc[6]/nss;
    double ssimB = acc[7]/nss;
    float r_loss   = (float)((1.0-ssimA)+m0+m1+m2);
    float out_loss = (float)((1.0-ssimB)+mse);
    float color    = colorsum * (1.0f/(float)(B_*C_*256));
    float gan      = gansum * (1.0f/(float)B_);
    float lightf   = (float)light;
    float loss = r_loss + lightf + 0.1f*color + out_loss + 0.05f*gan;
    out[0]=loss; out[1]=loss; out[2]=r_loss; out[3]=lightf;
    out[4]=color; out[5]=out_loss; out[6]=gan;
  }
}

extern "C" void kernel_launch(void* const* d_in, const int* in_sizes, int n_in,
                              void* d_out, int out_size, void* d_ws, size_t ws_size,
                              hipStream_t stream) {
  const float* img    = (const float*)d_in[0];
  const float* target = (const float*)d_in[1];
  const float* comp0  = (const float*)d_in[2];
  const float* comp1  = (const float*)d_in[3];
  const float* comp2  = (const float*)d_in[4];
  const float* rc0    = (const float*)d_in[5];
  const float* rc1    = (const float*)d_in[6];
  const float* chist  = (const float*)d_in[7];
  const float* score  = (const float*)d_in[8];

  double* acc = (double*)d_ws;                                   // 16 doubles
  unsigned int* bins = (unsigned int*)((char*)d_ws + 128);       // 48*256 uints

  hipMemsetAsync(d_ws, 0, 128 + (size_t)B_*C_*256*4, stream);

  k_elem<<<1024, 256, 0, stream>>>((const float4*)img,(const float4*)target,
                                   (const float4*)comp0,(const float4*)comp1,
                                   (const float4*)comp2,(const float4*)rc0,
                                   (const float4*)rc1, acc);
  k_hist<<<dim3(8, B_*C_), 256, 0, stream>>>((const float4*)target, bins);
  k_ssim<<<dim3((OUTW+ROWS-1)/ROWS, 2*B_*C_), 128, 0, stream>>>(comp0, rc0, img, target, acc);
  k_final<<<1, 256, 0, stream>>>(chist, score, acc, bins, (float*)d_out);
}